// Round 14
// baseline (1205.315 us; speedup 1.0000x reference)
//
#include <hip/hip_runtime.h>
#include <hip/hip_cooperative_groups.h>
#include <hip/hip_fp16.h>
#include <math.h>

namespace cg = cooperative_groups;

typedef _Float16 h2_t __attribute__((ext_vector_type(2)));
typedef _Float16 h4_t __attribute__((ext_vector_type(4)));
typedef _Float16 h8_t __attribute__((ext_vector_type(8)));
typedef float f4_t __attribute__((ext_vector_type(4)));
typedef float f8_t __attribute__((ext_vector_type(8)));

__device__ inline h8_t load8f_to_h8(const float* p) {
    float4 a = *(const float4*)p;
    float4 b = *(const float4*)(p + 4);
    h8_t r;
    r[0] = (_Float16)a.x; r[1] = (_Float16)a.y; r[2] = (_Float16)a.z; r[3] = (_Float16)a.w;
    r[4] = (_Float16)b.x; r[5] = (_Float16)b.y; r[6] = (_Float16)b.z; r[7] = (_Float16)b.w;
    return r;
}

__device__ inline h4_t load4f_to_h4(const float* p) {
    float4 a = *(const float4*)p;
    h4_t r;
    r[0] = (_Float16)a.x; r[1] = (_Float16)a.y; r[2] = (_Float16)a.z; r[3] = (_Float16)a.w;
    return r;
}

__device__ inline float dot8h(h8_t a, h8_t b, float s) {
    s = __builtin_amdgcn_fdot2(__builtin_shufflevector(a, a, 0, 1),
                               __builtin_shufflevector(b, b, 0, 1), s, false);
    s = __builtin_amdgcn_fdot2(__builtin_shufflevector(a, a, 2, 3),
                               __builtin_shufflevector(b, b, 2, 3), s, false);
    s = __builtin_amdgcn_fdot2(__builtin_shufflevector(a, a, 4, 5),
                               __builtin_shufflevector(b, b, 4, 5), s, false);
    s = __builtin_amdgcn_fdot2(__builtin_shufflevector(a, a, 6, 7),
                               __builtin_shufflevector(b, b, 6, 7), s, false);
    return s;
}

__device__ inline float dot4h(h4_t a, h4_t b, float s) {
    s = __builtin_amdgcn_fdot2(__builtin_shufflevector(a, a, 0, 1),
                               __builtin_shufflevector(b, b, 0, 1), s, false);
    s = __builtin_amdgcn_fdot2(__builtin_shufflevector(a, a, 2, 3),
                               __builtin_shufflevector(b, b, 2, 3), s, false);
    return s;
}

__device__ inline float elu1(float v) { return v > 0.f ? v : __expf(v) - 1.f; }

struct MA {
    const float* x;
    const float* eattr;
    const int* ei;
    const float *w1l, *b1l, *w1r, *b1r, *w1e, *att1, *bias1;
    const float *w2l, *b2l, *w2r, *b2r, *w2e, *att2, *bias2;
    const float *wc, *bc;
    float* out;
    _Float16 *xh, *xl1h, *xr1h, *h1h, *xl2h, *xr2h;
    _Float16 *p1l, *p1r, *p2l, *p2r;
    int *cnt, *offb, *rank;
    unsigned* flags;
    float* part;
    unsigned* edges;
    int N, E, NBs;
    float invE;
};

// ---- shared device phase helpers -----------------------------------------

__device__ inline void phase_packw(const MA& a, int g) {
    const float* W;
    _Float16* P;
    int M, lg;
    if (g < 2048)      { W = a.w1l; P = a.p1l; M = 128; lg = g; }
    else if (g < 4096) { W = a.w1r; P = a.p1r; M = 128; lg = g - 2048; }
    else if (g < 5120) { W = a.w2l; P = a.p2l; M = 64;  lg = g - 4096; }
    else               { W = a.w2r; P = a.p2r; M = 64;  lg = g - 5120; }
    int ln = lg & 63;
    int s = (lg >> 6) & 3;
    int tt = lg >> 8;
    int m = ln & 15, quad = ln >> 4;
    h8_t v;
#pragma unroll
    for (int j = 0; j < 8; ++j)
        v[j] = (_Float16)W[(size_t)(s * 32 + quad * 8 + j) * M + tt * 16 + m];
    *(h8_t*)(P + (size_t)lg * 8) = v;
}

// MFMA row tile: 16 rows x M cols x both weight matrices, NT = M/16
template <int NT>
__device__ inline void phase_mm_tile(const MA& a, const _Float16* X, int rt, int lane,
                                     const _Float16* Pl, const float* bl, _Float16* Yl,
                                     const _Float16* Pr, const float* br, _Float16* Yr) {
    int nrow = lane & 15, quad = lane >> 4;
    int row = rt * 16 + nrow;
    if (row >= a.N) return;
    const _Float16* xp = X + (size_t)row * 128 + quad * 8;
    h8_t bf0 = *(const h8_t*)(xp);
    h8_t bf1 = *(const h8_t*)(xp + 32);
    h8_t bf2 = *(const h8_t*)(xp + 64);
    h8_t bf3 = *(const h8_t*)(xp + 96);
#pragma unroll
    for (int w = 0; w < 2; ++w) {
        const _Float16* P = w ? Pr : Pl;
        const float* bias = w ? br : bl;
        _Float16* Y = w ? Yr : Yl;
#pragma unroll
        for (int t2 = 0; t2 < NT; ++t2) {
            f4_t acc = {0.f, 0.f, 0.f, 0.f};
            const _Float16* pb = P + (size_t)t2 * 2048 + (size_t)lane * 8;
            acc = __builtin_amdgcn_mfma_f32_16x16x32_f16(*(const h8_t*)pb, bf0, acc, 0, 0, 0);
            acc = __builtin_amdgcn_mfma_f32_16x16x32_f16(*(const h8_t*)(pb + 512), bf1, acc, 0, 0, 0);
            acc = __builtin_amdgcn_mfma_f32_16x16x32_f16(*(const h8_t*)(pb + 1024), bf2, acc, 0, 0, 0);
            acc = __builtin_amdgcn_mfma_f32_16x16x32_f16(*(const h8_t*)(pb + 1536), bf3, acc, 0, 0, 0);
            float4 bv = *(const float4*)(bias + t2 * 16 + quad * 4);
            h4_t o;
            o[0] = (_Float16)(acc[0] + bv.x);
            o[1] = (_Float16)(acc[1] + bv.y);
            o[2] = (_Float16)(acc[2] + bv.z);
            o[3] = (_Float16)(acc[3] + bv.w);
            *(h4_t*)(Y + (size_t)row * (NT * 16) + t2 * 16 + quad * 4) = o;
        }
    }
}

// layer-1 node pass body for one node (wave-cooperative)
__device__ inline void phase_node1_one(const MA& a, int node, int lane) {
    int g = lane >> 4;
    int q = lane & 15;
    int c0 = q * 8;
    h8_t xrv = *(const h8_t*)(a.xr1h + (size_t)node * 128 + c0);
    h8_t wev = load8f_to_h8(a.w1e + c0);
    h8_t atv = load8f_to_h8(a.att1 + c0);
    int start = a.offb[node];
    int deg1 = a.cnt[node] + 1;
    int last = deg1 - 1;
    float l = 0.f;
    f8_t acc = {0.f, 0.f, 0.f, 0.f, 0.f, 0.f, 0.f, 0.f};
    for (int i = 0; i < deg1; i += 16) {
        int s0 = i + g, s1 = i + 4 + g, s2 = i + 8 + g, s3 = i + 12 + g;
        unsigned p0 = a.edges[start + min(s0, last)];
        unsigned p1 = a.edges[start + min(s1, last)];
        unsigned p2 = a.edges[start + min(s2, last)];
        unsigned p3 = a.edges[start + min(s3, last)];
        h8_t x0 = *(const h8_t*)(a.xl1h + (size_t)(p0 & 0x00FFFFFFu) * 128 + c0);
        h8_t x1 = *(const h8_t*)(a.xl1h + (size_t)(p1 & 0x00FFFFFFu) * 128 + c0);
        h8_t x2 = *(const h8_t*)(a.xl1h + (size_t)(p2 & 0x00FFFFFFu) * 128 + c0);
        h8_t x3 = *(const h8_t*)(a.xl1h + (size_t)(p3 & 0x00FFFFFFu) * 128 + c0);
        float e0 = (float)(p0 >> 24) * (1.f / 255.f);
        float e1 = (float)(p1 >> 24) * (1.f / 255.f);
        float e2 = (float)(p2 >> 24) * (1.f / 255.f);
        float e3 = (float)(p3 >> 24) * (1.f / 255.f);
        h8_t z0 = x0 + xrv + wev * (_Float16)e0;
        z0 = __builtin_elementwise_max(z0, z0 * (_Float16)0.2f);
        float sc0 = dot8h(z0, atv, 0.f);
        h8_t z1 = x1 + xrv + wev * (_Float16)e1;
        z1 = __builtin_elementwise_max(z1, z1 * (_Float16)0.2f);
        float sc1 = dot8h(z1, atv, 0.f);
        h8_t z2 = x2 + xrv + wev * (_Float16)e2;
        z2 = __builtin_elementwise_max(z2, z2 * (_Float16)0.2f);
        float sc2 = dot8h(z2, atv, 0.f);
        h8_t z3 = x3 + xrv + wev * (_Float16)e3;
        z3 = __builtin_elementwise_max(z3, z3 * (_Float16)0.2f);
        float sc3 = dot8h(z3, atv, 0.f);
        sc0 += __shfl_xor(sc0, 1, 64); sc0 += __shfl_xor(sc0, 2, 64);
        sc1 += __shfl_xor(sc1, 1, 64); sc1 += __shfl_xor(sc1, 2, 64);
        sc2 += __shfl_xor(sc2, 1, 64); sc2 += __shfl_xor(sc2, 2, 64);
        sc3 += __shfl_xor(sc3, 1, 64); sc3 += __shfl_xor(sc3, 2, 64);
        float pA = (s0 < deg1) ? __expf(fminf(sc0, 60.f)) : 0.f;
        float pB = (s1 < deg1) ? __expf(fminf(sc1, 60.f)) : 0.f;
        float pC = (s2 < deg1) ? __expf(fminf(sc2, 60.f)) : 0.f;
        float pD = (s3 < deg1) ? __expf(fminf(sc3, 60.f)) : 0.f;
        l += (pA + pB) + (pC + pD);
#pragma unroll
        for (int k = 0; k < 8; ++k)
            acc[k] = fmaf(pA, (float)x0[k],
                     fmaf(pB, (float)x1[k],
                     fmaf(pC, (float)x2[k], fmaf(pD, (float)x3[k], acc[k]))));
    }
#pragma unroll
    for (int k = 0; k < 8; ++k) {
        acc[k] += __shfl_xor(acc[k], 16, 64);
        acc[k] += __shfl_xor(acc[k], 32, 64);
    }
    l += __shfl_xor(l, 16, 64);
    l += __shfl_xor(l, 32, 64);
    if (g == 0) {
        float inv = 1.f / l;
        float4 b0 = *(const float4*)(a.bias1 + c0);
        float4 b1 = *(const float4*)(a.bias1 + c0 + 4);
        float bb[8] = {b0.x, b0.y, b0.z, b0.w, b1.x, b1.y, b1.z, b1.w};
        h8_t o;
#pragma unroll
        for (int k = 0; k < 8; ++k) o[k] = (_Float16)elu1(fmaf(acc[k], inv, bb[k]));
        *(h8_t*)(a.h1h + (size_t)node * 128 + c0) = o;
    }
}

// layer-2 node pass + classifier for one block-tile of 16 nodes
__device__ inline void phase_node2_tile(const MA& a, int tb, int tid,
                                        float (*h2s)[33]) {
    int lane = tid & 63;
    int wib = tid >> 6;
    int sub = lane >> 4;
    int r = lane & 15;
    int nloc = wib * 4 + sub;
    int c0 = r * 4;
    int node = tb * 16 + nloc;
    if (node < a.N) {
        h4_t xrv = *(const h4_t*)(a.xr2h + (size_t)node * 64 + c0);
        h4_t wev = load4f_to_h4(a.w2e + c0);
        h4_t atv = load4f_to_h4(a.att2 + c0);
        int start = a.offb[node];
        int deg1 = a.cnt[node] + 1;
        int last = deg1 - 1;
        float l = 0.f;
        float acc[4] = {0.f, 0.f, 0.f, 0.f};
        for (int i = 0; i < deg1; i += 4) {
            unsigned p[4];
            h4_t xv[4];
#pragma unroll
            for (int j = 0; j < 4; ++j) p[j] = a.edges[start + min(i + j, last)];
#pragma unroll
            for (int j = 0; j < 4; ++j)
                xv[j] = *(const h4_t*)(a.xl2h + (size_t)(p[j] & 0x00FFFFFFu) * 64 + c0);
#pragma unroll
            for (int j = 0; j < 4; ++j) {
                float ea = (float)(p[j] >> 24) * (1.f / 255.f);
                h4_t z = xv[j] + xrv + wev * (_Float16)ea;
                z = __builtin_elementwise_max(z, z * (_Float16)0.2f);
                float sc = dot4h(z, atv, 0.f);
                sc += __shfl_xor(sc, 1, 64);
                sc += __shfl_xor(sc, 2, 64);
                sc += __shfl_xor(sc, 4, 64);
                float pp = (i + j < deg1) ? __expf(fminf(sc, 60.f)) : 0.f;
                l += pp;
#pragma unroll
                for (int k = 0; k < 4; ++k) acc[k] = fmaf(pp, (float)xv[j][k], acc[k]);
            }
        }
        float inv = 1.f / l;
#pragma unroll
        for (int k = 0; k < 4; ++k) {
            float norm = acc[k] * inv;
            float other = __shfl_xor(norm, 8, 64);
            float v = 0.5f * (norm + other);
            if (r < 8) h2s[nloc][c0 + k] = elu1(v + a.bias2[c0 + k]);
        }
    }
    __syncthreads();
    if (tid < 128) {
        int n = tid >> 3, j = tid & 7;
        int gnode = tb * 16 + n;
        if (gnode < a.N) {
            float acc = a.bc[j];
#pragma unroll 8
            for (int d = 0; d < 32; ++d) acc = fmaf(h2s[n][d], a.wc[d * 8 + j], acc);
            a.out[(size_t)gnode * 8 + j] = acc;
        }
    }
    __syncthreads();
}

// ================= cooperative mega kernel ================================

__global__ __launch_bounds__(256, 4) void k_mega(MA a) {
    cg::grid_group grid = cg::this_grid();
    const int G = (int)gridDim.x;
    const int bid = blockIdx.x;
    const int tid = threadIdx.x;
    const int t = bid * 256 + tid;
    const int stride = G * 256;
    const int lane = tid & 63;
    const int wib = tid >> 6;
    const int wv = bid * 4 + wib;
    const int nw = G * 4;

    __shared__ float sdf[4];
    __shared__ int tmp[256];
    __shared__ int sbase;
    __shared__ float smean_s;
    __shared__ float h2s[16][33];

    // P0: zero cnt/flags, x->fp16, pack W, eattr partials
    for (int i = t; i < a.N; i += stride) a.cnt[i] = 0;
    for (int i = t; i < a.NBs; i += stride) a.flags[i] = 0u;
    {
        int nchunk = (a.N * 128) >> 3;
        for (int i = t; i < nchunk; i += stride) {
            h8_t v = load8f_to_h8(a.x + (size_t)i * 8);
            *(h8_t*)(a.xh + (size_t)i * 8) = v;
        }
    }
    for (int g = t; g < 6144; g += stride) phase_packw(a, g);
    {
        float s = 0.f;
        for (int i = t; i < a.E; i += stride) s += a.eattr[i];
        for (int o = 1; o < 64; o <<= 1) s += __shfl_xor(s, o, 64);
        if (lane == 0) sdf[wib] = s;
        __syncthreads();
        if (tid == 0) a.part[bid] = sdf[0] + sdf[1] + sdf[2] + sdf[3];
    }
    __threadfence();
    grid.sync();
    __threadfence();

    // P1: first half counts (atomics), second half runs layer-1 MFMA
    {
        int half = G >> 1;
        if (bid < half) {
            int t1 = bid * 256 + tid;
            const int s1 = half * 256;
            for (int e = t1; e < a.E; e += s1)
                a.rank[e] = atomicAdd(&a.cnt[a.ei[a.E + e]], 1);
        } else {
            int mwv = (bid - half) * 4 + wib;
            const int mnw = (G - half) * 4;
            int ntile = (a.N + 15) / 16;
            for (int rt = mwv; rt < ntile; rt += mnw)
                phase_mm_tile<8>(a, a.xh, rt, lane, a.p1l, a.b1l, a.xl1h, a.p1r, a.b1r, a.xr1h);
        }
    }
    __threadfence();
    grid.sync();
    __threadfence();

    // P2: decoupled-lookback scan of (cnt+1), offsets + self-loop records
    if (bid < a.NBs) {
        {
            float s = 0.f;
            for (int i2 = tid; i2 < G; i2 += 256) s += a.part[i2];
            for (int o = 1; o < 64; o <<= 1) s += __shfl_xor(s, o, 64);
            if (lane == 0) sdf[wib] = s;
            __syncthreads();
            if (tid == 0) smean_s = (sdf[0] + sdf[1] + sdf[2] + sdf[3]) * a.invE;
        }
        int i = bid * 256 + tid;
        int v = (i < a.N) ? a.cnt[i] + 1 : 0;
        tmp[tid] = v;
        __syncthreads();
        for (int o = 1; o < 256; o <<= 1) {
            int tv = (tid >= o) ? tmp[tid - o] : 0;
            __syncthreads();
            tmp[tid] += tv;
            __syncthreads();
        }
        int T = tmp[255];
        if (tid == 0) {
            if (bid == 0) {
                atomicExch(&a.flags[0], (2u << 30) | (unsigned)T);
                sbase = 0;
            } else {
                atomicExch(&a.flags[bid], (1u << 30) | (unsigned)T);
                int running = 0;
                int j = bid - 1;
                while (true) {
                    unsigned f = atomicAdd(&a.flags[j], 0u);
                    unsigned st = f >> 30;
                    if (st == 0u) continue;
                    running += (int)(f & 0x3FFFFFFFu);
                    if (st == 2u) break;
                    --j;
                }
                atomicExch(&a.flags[bid], (2u << 30) | (unsigned)(running + T));
                sbase = running;
            }
        }
        __syncthreads();
        if (i < a.N) {
            int o = sbase + tmp[tid] - v;
            a.offb[i] = o;
            unsigned qv = (unsigned)__float2int_rn(smean_s * 255.f);
            a.edges[o] = (unsigned)i | (qv << 24);
        }
    }
    __threadfence();
    grid.sync();
    __threadfence();

    // P3: atomic-free edge scatter
    for (int e = t; e < a.E; e += stride) {
        int d = a.ei[a.E + e];
        int pos = a.offb[d] + 1 + a.rank[e];
        unsigned qv = (unsigned)__float2int_rn(a.eattr[e] * 255.f);
        a.edges[pos] = (unsigned)a.ei[e] | (qv << 24);
    }
    __threadfence();
    grid.sync();
    __threadfence();

    // P4: layer-1 node pass
    for (int node = wv; node < a.N; node += nw) phase_node1_one(a, node, lane);
    __threadfence();
    grid.sync();
    __threadfence();

    // P5: layer-2 MFMA GEMM
    {
        int ntile = (a.N + 15) / 16;
        for (int rt = wv; rt < ntile; rt += nw)
            phase_mm_tile<4>(a, a.h1h, rt, lane, a.p2l, a.b2l, a.xl2h, a.p2r, a.b2r, a.xr2h);
    }
    __threadfence();
    grid.sync();
    __threadfence();

    // P6: layer-2 node pass + classifier
    {
        int ntile = (a.N + 15) / 16;
        for (int tb = bid; tb < ntile; tb += G) phase_node2_tile(a, tb, tid, h2s);
    }
}

// ================= fallback multi-kernel path (R11, proven) ===============

__global__ __launch_bounds__(256) void k_pre_fb(MA a) {
    if (blockIdx.x >= 256) {
        int g = (blockIdx.x - 256) * 256 + threadIdx.x;
        if (g < 6144) phase_packw(a, g);
        return;
    }
    int t = blockIdx.x * 256 + threadIdx.x;
    const int stride = 256 * 256;
    for (int i = t; i < a.NBs; i += stride) a.flags[i] = 0u;
    int nchunk = (a.N * 128) >> 3;
    for (int i = t; i < nchunk; i += stride) {
        h8_t v = load8f_to_h8(a.x + (size_t)i * 8);
        *(h8_t*)(a.xh + (size_t)i * 8) = v;
    }
    for (int e = t; e < a.E; e += stride) a.rank[e] = atomicAdd(&a.cnt[a.ei[a.E + e]], 1);
    float s = 0.f;
    for (int i = t; i < a.E; i += stride) s += a.eattr[i];
    __shared__ float sd[4];
    for (int o = 1; o < 64; o <<= 1) s += __shfl_xor(s, o, 64);
    if ((threadIdx.x & 63) == 0) sd[threadIdx.x >> 6] = s;
    __syncthreads();
    if (threadIdx.x == 0) a.part[blockIdx.x] = sd[0] + sd[1] + sd[2] + sd[3];
}

__global__ __launch_bounds__(256, 1) void k_scan_fb(MA a) {
    __shared__ int tmp[256];
    __shared__ int sbase;
    __shared__ float smean;
    int tx = threadIdx.x;
    int b = blockIdx.x;
    int i = b * 256 + tx;
    {
        float s = a.part[tx];  // 256 partials
        for (int o = 1; o < 64; o <<= 1) s += __shfl_xor(s, o, 64);
        __shared__ float sd[4];
        if ((tx & 63) == 0) sd[tx >> 6] = s;
        __syncthreads();
        if (tx == 0) smean = (sd[0] + sd[1] + sd[2] + sd[3]) * a.invE;
    }
    int v = (i < a.N) ? a.cnt[i] + 1 : 0;
    tmp[tx] = v;
    __syncthreads();
    for (int o = 1; o < 256; o <<= 1) {
        int tv = (tx >= o) ? tmp[tx - o] : 0;
        __syncthreads();
        tmp[tx] += tv;
        __syncthreads();
    }
    int T = tmp[255];
    if (tx == 0) {
        if (b == 0) {
            atomicExch(&a.flags[0], (2u << 30) | (unsigned)T);
            sbase = 0;
        } else {
            atomicExch(&a.flags[b], (1u << 30) | (unsigned)T);
            int running = 0;
            int j = b - 1;
            while (true) {
                unsigned f = atomicAdd(&a.flags[j], 0u);
                unsigned st = f >> 30;
                if (st == 0u) continue;
                running += (int)(f & 0x3FFFFFFFu);
                if (st == 2u) break;
                --j;
            }
            atomicExch(&a.flags[b], (2u << 30) | (unsigned)(running + T));
            sbase = running;
        }
    }
    __syncthreads();
    if (i < a.N) {
        int o = sbase + tmp[tx] - v;
        a.offb[i] = o;
        unsigned qv = (unsigned)__float2int_rn(smean * 255.f);
        a.edges[o] = (unsigned)i | (qv << 24);
    }
}

__global__ __launch_bounds__(256) void k_fill_fb(MA a) {
    int e = blockIdx.x * 256 + threadIdx.x;
    if (e >= a.E) return;
    int d = a.ei[a.E + e];
    int pos = a.offb[d] + 1 + a.rank[e];
    unsigned qv = (unsigned)__float2int_rn(a.eattr[e] * 255.f);
    a.edges[pos] = (unsigned)a.ei[e] | (qv << 24);
}

template <int NT>
__global__ __launch_bounds__(256) void k_mm_fb(MA a) {
    int wid = blockIdx.x * 4 + (threadIdx.x >> 6);
    int lane = threadIdx.x & 63;
    int ntile = (a.N + 15) / 16;
    if (wid >= ntile) return;
    if (NT == 8)
        phase_mm_tile<8>(a, a.xh, wid, lane, a.p1l, a.b1l, a.xl1h, a.p1r, a.b1r, a.xr1h);
    else
        phase_mm_tile<4>(a, a.h1h, wid, lane, a.p2l, a.b2l, a.xl2h, a.p2r, a.b2r, a.xr2h);
}

__global__ __launch_bounds__(256) void k_node1_fb(MA a) {
    int node = blockIdx.x * 4 + (threadIdx.x >> 6);
    if (node >= a.N) return;
    phase_node1_one(a, node, threadIdx.x & 63);
}

__global__ __launch_bounds__(256) void k_node2_fb(MA a) {
    __shared__ float h2s[16][33];
    int ntile = (a.N + 15) / 16;
    if ((int)blockIdx.x >= ntile) return;
    phase_node2_tile(a, blockIdx.x, threadIdx.x, h2s);
}

// ---- launch --------------------------------------------------------------

extern "C" void kernel_launch(void* const* d_in, const int* in_sizes, int n_in,
                              void* d_out, int out_size, void* d_ws, size_t ws_size,
                              hipStream_t stream) {
    const int N = in_sizes[0] / 128;
    const int E = in_sizes[2];
    const int tot = E + N;

    char* ws = (char*)d_ws;
    size_t o = 0;
    auto alloc = [&](size_t bytes) -> void* {
        void* p = ws + o;
        o += (bytes + 255) & ~(size_t)255;
        return p;
    };
    MA a;
    a.x     = (const float*)d_in[0];
    a.ei    = (const int*)d_in[1];
    a.eattr = (const float*)d_in[2];
    a.w1l = (const float*)d_in[3];  a.b1l = (const float*)d_in[4];
    a.w1r = (const float*)d_in[5];  a.b1r = (const float*)d_in[6];
    a.w1e = (const float*)d_in[7];  a.att1 = (const float*)d_in[8];
    a.bias1 = (const float*)d_in[9];
    a.w2l = (const float*)d_in[10]; a.b2l = (const float*)d_in[11];
    a.w2r = (const float*)d_in[12]; a.b2r = (const float*)d_in[13];
    a.w2e = (const float*)d_in[14]; a.att2 = (const float*)d_in[15];
    a.bias2 = (const float*)d_in[16];
    a.wc = (const float*)d_in[17];  a.bc = (const float*)d_in[18];
    a.out = (float*)d_out;

    a.xh   = (_Float16*)alloc((size_t)N * 128 * 2);
    a.xl1h = (_Float16*)alloc((size_t)N * 128 * 2);
    a.xr1h = (_Float16*)alloc((size_t)N * 128 * 2);
    a.h1h  = (_Float16*)alloc((size_t)N * 128 * 2);
    a.xl2h = (_Float16*)alloc((size_t)N * 64 * 2);
    a.xr2h = (_Float16*)alloc((size_t)N * 64 * 2);
    a.p1l  = (_Float16*)alloc(128 * 128 * 2);
    a.p1r  = (_Float16*)alloc(128 * 128 * 2);
    a.p2l  = (_Float16*)alloc(128 * 64 * 2);
    a.p2r  = (_Float16*)alloc(128 * 64 * 2);
    a.cnt  = (int*)alloc((size_t)N * 4);
    a.offb = (int*)alloc((size_t)N * 4);
    a.rank = (int*)alloc((size_t)E * 4);
    a.flags = (unsigned*)alloc(1024 * 4);
    a.part  = (float*)alloc(1024 * 4);
    a.edges = (unsigned*)alloc((size_t)tot * 4);
    a.N = N;
    a.E = E;
    a.NBs = (N + 255) / 256;
    a.invE = 1.0f / (float)E;

    // size cooperative grid from the runtime's own occupancy result
    int dev = 0;
    hipGetDevice(&dev);
    int numCU = 0;
    hipDeviceGetAttribute(&numCU, hipDeviceAttributeMultiprocessorCount, dev);
    int maxB = 0;
    hipError_t qerr =
        hipOccupancyMaxActiveBlocksPerMultiprocessor(&maxB, (const void*)k_mega, 256, 0);
    int grid = (qerr == hipSuccess && numCU > 0) ? maxB * numCU : 0;
    if (grid > 1024) grid = 1024;

    hipError_t lerr = hipErrorUnknown;
    if (grid >= a.NBs && grid >= 64) {
        void* kargs[] = {&a};
        lerr = hipLaunchCooperativeKernel((void*)k_mega, dim3(grid), dim3(256), kargs, 0, stream);
    }
    if (lerr != hipSuccess) {
        // proven multi-kernel fallback (R11)
        hipMemsetAsync(a.cnt, 0, (size_t)N * 4, stream);
        k_pre_fb<<<280, 256, 0, stream>>>(a);
        k_scan_fb<<<a.NBs, 256, 0, stream>>>(a);
        k_fill_fb<<<(E + 255) / 256, 256, 0, stream>>>(a);
        k_mm_fb<8><<<(N + 63) / 64, 256, 0, stream>>>(a);
        k_node1_fb<<<(N + 3) / 4, 256, 0, stream>>>(a);
        k_mm_fb<4><<<(N + 63) / 64, 256, 0, stream>>>(a);
        k_node2_fb<<<(N + 15) / 16, 256, 0, stream>>>(a);
    }
}

// Round 15
// 277.748 us; speedup vs baseline: 4.3396x; 4.3396x over previous
//
#include <hip/hip_runtime.h>
#include <hip/hip_fp16.h>
#include <math.h>

typedef _Float16 h2_t __attribute__((ext_vector_type(2)));
typedef _Float16 h4_t __attribute__((ext_vector_type(4)));
typedef _Float16 h8_t __attribute__((ext_vector_type(8)));
typedef float f4_t __attribute__((ext_vector_type(4)));
typedef float f8_t __attribute__((ext_vector_type(8)));

#define PRE_BLOCKS 512

__device__ inline h8_t load8f_to_h8(const float* p) {
    float4 a = *(const float4*)p;
    float4 b = *(const float4*)(p + 4);
    h8_t r;
    r[0] = (_Float16)a.x; r[1] = (_Float16)a.y; r[2] = (_Float16)a.z; r[3] = (_Float16)a.w;
    r[4] = (_Float16)b.x; r[5] = (_Float16)b.y; r[6] = (_Float16)b.z; r[7] = (_Float16)b.w;
    return r;
}

__device__ inline h4_t load4f_to_h4(const float* p) {
    float4 a = *(const float4*)p;
    h4_t r;
    r[0] = (_Float16)a.x; r[1] = (_Float16)a.y; r[2] = (_Float16)a.z; r[3] = (_Float16)a.w;
    return r;
}

__device__ inline float dot8h(h8_t a, h8_t b, float s) {
    s = __builtin_amdgcn_fdot2(__builtin_shufflevector(a, a, 0, 1),
                               __builtin_shufflevector(b, b, 0, 1), s, false);
    s = __builtin_amdgcn_fdot2(__builtin_shufflevector(a, a, 2, 3),
                               __builtin_shufflevector(b, b, 2, 3), s, false);
    s = __builtin_amdgcn_fdot2(__builtin_shufflevector(a, a, 4, 5),
                               __builtin_shufflevector(b, b, 4, 5), s, false);
    s = __builtin_amdgcn_fdot2(__builtin_shufflevector(a, a, 6, 7),
                               __builtin_shufflevector(b, b, 6, 7), s, false);
    return s;
}

__device__ inline float dot4h(h4_t a, h4_t b, float s) {
    s = __builtin_amdgcn_fdot2(__builtin_shufflevector(a, a, 0, 1),
                               __builtin_shufflevector(b, b, 0, 1), s, false);
    s = __builtin_amdgcn_fdot2(__builtin_shufflevector(a, a, 2, 3),
                               __builtin_shufflevector(b, b, 2, 3), s, false);
    return s;
}

__device__ inline float elu1(float v) { return v > 0.f ? v : __expf(v) - 1.f; }

struct MA {
    const float* x;
    const float* eattr;
    const int* ei;
    const float *w1l, *b1l, *w1r, *b1r, *w1e, *att1, *bias1;
    const float *w2l, *b2l, *w2r, *b2r, *w2e, *att2, *bias2;
    const float *wc, *bc;
    float* out;
    _Float16 *xh, *xl1h, *xr1h, *h1h, *xl2h, *xr2h;
    _Float16 *p1l, *p1r, *p2l, *p2r;
    int *cnt, *offb, *rank;
    unsigned* flags;
    float* part;
    unsigned* edges;
    int N, E, NBs, NW;
    float invE;
};

// ---- phase helpers -------------------------------------------------------

__device__ inline void phase_packw(const MA& a, int g) {
    const float* W;
    _Float16* P;
    int M, lg;
    if (g < 2048)      { W = a.w1l; P = a.p1l; M = 128; lg = g; }
    else if (g < 4096) { W = a.w1r; P = a.p1r; M = 128; lg = g - 2048; }
    else if (g < 5120) { W = a.w2l; P = a.p2l; M = 64;  lg = g - 4096; }
    else               { W = a.w2r; P = a.p2r; M = 64;  lg = g - 5120; }
    int ln = lg & 63;
    int s = (lg >> 6) & 3;
    int tt = lg >> 8;
    int m = ln & 15, quad = ln >> 4;
    h8_t v;
#pragma unroll
    for (int j = 0; j < 8; ++j)
        v[j] = (_Float16)W[(size_t)(s * 32 + quad * 8 + j) * M + tt * 16 + m];
    *(h8_t*)(P + (size_t)lg * 8) = v;
}

template <int NT>
__device__ inline void phase_mm_tile(const MA& a, const _Float16* X, int rt, int lane,
                                     const _Float16* Pl, const float* bl, _Float16* Yl,
                                     const _Float16* Pr, const float* br, _Float16* Yr) {
    int nrow = lane & 15, quad = lane >> 4;
    int row = rt * 16 + nrow;
    if (row >= a.N) return;
    const _Float16* xp = X + (size_t)row * 128 + quad * 8;
    h8_t bf0 = *(const h8_t*)(xp);
    h8_t bf1 = *(const h8_t*)(xp + 32);
    h8_t bf2 = *(const h8_t*)(xp + 64);
    h8_t bf3 = *(const h8_t*)(xp + 96);
#pragma unroll
    for (int w = 0; w < 2; ++w) {
        const _Float16* P = w ? Pr : Pl;
        const float* bias = w ? br : bl;
        _Float16* Y = w ? Yr : Yl;
#pragma unroll
        for (int t2 = 0; t2 < NT; ++t2) {
            f4_t acc = {0.f, 0.f, 0.f, 0.f};
            const _Float16* pb = P + (size_t)t2 * 2048 + (size_t)lane * 8;
            acc = __builtin_amdgcn_mfma_f32_16x16x32_f16(*(const h8_t*)pb, bf0, acc, 0, 0, 0);
            acc = __builtin_amdgcn_mfma_f32_16x16x32_f16(*(const h8_t*)(pb + 512), bf1, acc, 0, 0, 0);
            acc = __builtin_amdgcn_mfma_f32_16x16x32_f16(*(const h8_t*)(pb + 1024), bf2, acc, 0, 0, 0);
            acc = __builtin_amdgcn_mfma_f32_16x16x32_f16(*(const h8_t*)(pb + 1536), bf3, acc, 0, 0, 0);
            float4 bv = *(const float4*)(bias + t2 * 16 + quad * 4);
            h4_t o;
            o[0] = (_Float16)(acc[0] + bv.x);
            o[1] = (_Float16)(acc[1] + bv.y);
            o[2] = (_Float16)(acc[2] + bv.z);
            o[3] = (_Float16)(acc[3] + bv.w);
            *(h4_t*)(Y + (size_t)row * (NT * 16) + t2 * 16 + quad * 4) = o;
        }
    }
}

// ---- k_pre: zero cnt/flags, x->fp16, eattr partials; tail blocks pack W --

__global__ __launch_bounds__(256) void k_pre(MA a) {
    if (blockIdx.x >= PRE_BLOCKS) {
        int g = (blockIdx.x - PRE_BLOCKS) * 256 + threadIdx.x;
        if (g < 6144) phase_packw(a, g);
        return;
    }
    int t = blockIdx.x * 256 + threadIdx.x;
    const int stride = PRE_BLOCKS * 256;
    for (int i = t; i < a.N; i += stride) a.cnt[i] = 0;
    for (int i = t; i < a.NBs; i += stride) a.flags[i] = 0u;
    int nchunk = (a.N * 128) >> 3;
    for (int i = t; i < nchunk; i += stride) {
        h8_t v = load8f_to_h8(a.x + (size_t)i * 8);
        *(h8_t*)(a.xh + (size_t)i * 8) = v;
    }
    float s = 0.f;
    for (int i = t; i < a.E; i += stride) s += a.eattr[i];
    __shared__ float sd[4];
    for (int o = 1; o < 64; o <<= 1) s += __shfl_xor(s, o, 64);
    if ((threadIdx.x & 63) == 0) sd[threadIdx.x >> 6] = s;
    __syncthreads();
    if (threadIdx.x == 0) a.part[blockIdx.x] = sd[0] + sd[1] + sd[2] + sd[3];
}

// ---- k_mmcnt: blocks [0,NW) run layer-1 MFMA GEMM; blocks [NW,..) run the
// atomic count+rank pass. Independent outputs -> no sync needed; duration
// is max(gemm, count) instead of sum.

#define CNT_BLOCKS 1600

__global__ __launch_bounds__(256) void k_mmcnt(MA a) {
    int bid = blockIdx.x;
    if (bid < a.NW) {
        int wid = bid * 4 + (threadIdx.x >> 6);
        int ntile = (a.N + 15) / 16;
        if (wid < ntile)
            phase_mm_tile<8>(a, a.xh, wid, threadIdx.x & 63,
                             a.p1l, a.b1l, a.xl1h, a.p1r, a.b1r, a.xr1h);
    } else {
        int t = (bid - a.NW) * 256 + threadIdx.x;
        const int stride = CNT_BLOCKS * 256;
        for (int e = t; e < a.E; e += stride)
            a.rank[e] = atomicAdd(&a.cnt[a.ei[a.E + e]], 1);
    }
}

// ---- k_scan: decoupled-lookback scan of (cnt+1) + offsets + self-loops ---

__global__ __launch_bounds__(256, 1) void k_scan(MA a) {
    __shared__ int tmp[256];
    __shared__ int sbase;
    __shared__ float smean;
    int tx = threadIdx.x;
    int b = blockIdx.x;
    int i = b * 256 + tx;
    {
        float s = a.part[tx] + a.part[tx + 256];  // PRE_BLOCKS=512 partials
        for (int o = 1; o < 64; o <<= 1) s += __shfl_xor(s, o, 64);
        __shared__ float sd[4];
        if ((tx & 63) == 0) sd[tx >> 6] = s;
        __syncthreads();
        if (tx == 0) smean = (sd[0] + sd[1] + sd[2] + sd[3]) * a.invE;
    }
    int v = (i < a.N) ? a.cnt[i] + 1 : 0;
    tmp[tx] = v;
    __syncthreads();
    for (int o = 1; o < 256; o <<= 1) {
        int tv = (tx >= o) ? tmp[tx - o] : 0;
        __syncthreads();
        tmp[tx] += tv;
        __syncthreads();
    }
    int T = tmp[255];
    if (tx == 0) {
        if (b == 0) {
            atomicExch(&a.flags[0], (2u << 30) | (unsigned)T);
            sbase = 0;
        } else {
            atomicExch(&a.flags[b], (1u << 30) | (unsigned)T);
            int running = 0;
            int j = b - 1;
            while (true) {
                unsigned f = atomicAdd(&a.flags[j], 0u);
                unsigned st = f >> 30;
                if (st == 0u) continue;
                running += (int)(f & 0x3FFFFFFFu);
                if (st == 2u) break;
                --j;
            }
            atomicExch(&a.flags[b], (2u << 30) | (unsigned)(running + T));
            sbase = running;
        }
    }
    __syncthreads();
    if (i < a.N) {
        int o = sbase + tmp[tx] - v;
        a.offb[i] = o;
        unsigned qv = (unsigned)__float2int_rn(smean * 255.f);
        a.edges[o] = (unsigned)i | (qv << 24);
    }
}

// ---- k_fill: atomic-free scatter (pos = off[dst] + 1 + rank[e]) ----------

__global__ __launch_bounds__(256) void k_fill(MA a) {
    int e = blockIdx.x * 256 + threadIdx.x;
    if (e >= a.E) return;
    int d = a.ei[a.E + e];
    int pos = a.offb[d] + 1 + a.rank[e];
    unsigned qv = (unsigned)__float2int_rn(a.eattr[e] * 255.f);
    a.edges[pos] = (unsigned)a.ei[e] | (qv << 24);
}

// ---- k_node1: layer-1 node pass (wave per node; 4 gathers in flight) -----

__global__ __launch_bounds__(256) void k_node1(MA a) {
    int lane = threadIdx.x & 63;
    int node = blockIdx.x * 4 + (threadIdx.x >> 6);
    if (node >= a.N) return;
    int g = lane >> 4;
    int q = lane & 15;
    int c0 = q * 8;

    h8_t xrv = *(const h8_t*)(a.xr1h + (size_t)node * 128 + c0);
    h8_t wev = load8f_to_h8(a.w1e + c0);
    h8_t atv = load8f_to_h8(a.att1 + c0);
    int start = a.offb[node];
    int deg1 = a.cnt[node] + 1;
    int last = deg1 - 1;

    float l = 0.f;
    f8_t acc = {0.f, 0.f, 0.f, 0.f, 0.f, 0.f, 0.f, 0.f};
    for (int i = 0; i < deg1; i += 16) {
        int s0 = i + g, s1 = i + 4 + g, s2 = i + 8 + g, s3 = i + 12 + g;
        unsigned p0 = a.edges[start + min(s0, last)];
        unsigned p1 = a.edges[start + min(s1, last)];
        unsigned p2 = a.edges[start + min(s2, last)];
        unsigned p3 = a.edges[start + min(s3, last)];
        h8_t x0 = *(const h8_t*)(a.xl1h + (size_t)(p0 & 0x00FFFFFFu) * 128 + c0);
        h8_t x1 = *(const h8_t*)(a.xl1h + (size_t)(p1 & 0x00FFFFFFu) * 128 + c0);
        h8_t x2 = *(const h8_t*)(a.xl1h + (size_t)(p2 & 0x00FFFFFFu) * 128 + c0);
        h8_t x3 = *(const h8_t*)(a.xl1h + (size_t)(p3 & 0x00FFFFFFu) * 128 + c0);
        float e0 = (float)(p0 >> 24) * (1.f / 255.f);
        float e1 = (float)(p1 >> 24) * (1.f / 255.f);
        float e2 = (float)(p2 >> 24) * (1.f / 255.f);
        float e3 = (float)(p3 >> 24) * (1.f / 255.f);
        h8_t z0 = x0 + xrv + wev * (_Float16)e0;
        z0 = __builtin_elementwise_max(z0, z0 * (_Float16)0.2f);
        float sc0 = dot8h(z0, atv, 0.f);
        h8_t z1 = x1 + xrv + wev * (_Float16)e1;
        z1 = __builtin_elementwise_max(z1, z1 * (_Float16)0.2f);
        float sc1 = dot8h(z1, atv, 0.f);
        h8_t z2 = x2 + xrv + wev * (_Float16)e2;
        z2 = __builtin_elementwise_max(z2, z2 * (_Float16)0.2f);
        float sc2 = dot8h(z2, atv, 0.f);
        h8_t z3 = x3 + xrv + wev * (_Float16)e3;
        z3 = __builtin_elementwise_max(z3, z3 * (_Float16)0.2f);
        float sc3 = dot8h(z3, atv, 0.f);
        sc0 += __shfl_xor(sc0, 1, 64); sc0 += __shfl_xor(sc0, 2, 64);
        sc1 += __shfl_xor(sc1, 1, 64); sc1 += __shfl_xor(sc1, 2, 64);
        sc2 += __shfl_xor(sc2, 1, 64); sc2 += __shfl_xor(sc2, 2, 64);
        sc3 += __shfl_xor(sc3, 1, 64); sc3 += __shfl_xor(sc3, 2, 64);
        float pA = (s0 < deg1) ? __expf(fminf(sc0, 60.f)) : 0.f;
        float pB = (s1 < deg1) ? __expf(fminf(sc1, 60.f)) : 0.f;
        float pC = (s2 < deg1) ? __expf(fminf(sc2, 60.f)) : 0.f;
        float pD = (s3 < deg1) ? __expf(fminf(sc3, 60.f)) : 0.f;
        l += (pA + pB) + (pC + pD);
#pragma unroll
        for (int k = 0; k < 8; ++k)
            acc[k] = fmaf(pA, (float)x0[k],
                     fmaf(pB, (float)x1[k],
                     fmaf(pC, (float)x2[k], fmaf(pD, (float)x3[k], acc[k]))));
    }
#pragma unroll
    for (int k = 0; k < 8; ++k) {
        acc[k] += __shfl_xor(acc[k], 16, 64);
        acc[k] += __shfl_xor(acc[k], 32, 64);
    }
    l += __shfl_xor(l, 16, 64);
    l += __shfl_xor(l, 32, 64);
    if (g == 0) {
        float inv = 1.f / l;
        float4 b0 = *(const float4*)(a.bias1 + c0);
        float4 b1 = *(const float4*)(a.bias1 + c0 + 4);
        float bb[8] = {b0.x, b0.y, b0.z, b0.w, b1.x, b1.y, b1.z, b1.w};
        h8_t o;
#pragma unroll
        for (int k = 0; k < 8; ++k) o[k] = (_Float16)elu1(fmaf(acc[k], inv, bb[k]));
        *(h8_t*)(a.h1h + (size_t)node * 128 + c0) = o;
    }
}

// ---- k_mm4: layer-2 MFMA GEMM --------------------------------------------

__global__ __launch_bounds__(256) void k_mm4(MA a) {
    int wid = blockIdx.x * 4 + (threadIdx.x >> 6);
    int ntile = (a.N + 15) / 16;
    if (wid >= ntile) return;
    phase_mm_tile<4>(a, a.h1h, wid, threadIdx.x & 63,
                     a.p2l, a.b2l, a.xl2h, a.p2r, a.b2r, a.xr2h);
}

// ---- k_node2: layer-2 node pass + fused classifier -----------------------

__global__ __launch_bounds__(256) void k_node2(MA a) {
    __shared__ float h2s[16][33];
    int tid = threadIdx.x;
    int lane = tid & 63;
    int wib = tid >> 6;
    int sub = lane >> 4;
    int r = lane & 15;
    int nloc = wib * 4 + sub;
    int node = blockIdx.x * 16 + nloc;
    int c0 = r * 4;

    if (node < a.N) {
        h4_t xrv = *(const h4_t*)(a.xr2h + (size_t)node * 64 + c0);
        h4_t wev = load4f_to_h4(a.w2e + c0);
        h4_t atv = load4f_to_h4(a.att2 + c0);
        int start = a.offb[node];
        int deg1 = a.cnt[node] + 1;
        int last = deg1 - 1;
        float l = 0.f;
        float acc[4] = {0.f, 0.f, 0.f, 0.f};
        for (int i = 0; i < deg1; i += 4) {
            unsigned p[4];
            h4_t xv[4];
#pragma unroll
            for (int j = 0; j < 4; ++j) p[j] = a.edges[start + min(i + j, last)];
#pragma unroll
            for (int j = 0; j < 4; ++j)
                xv[j] = *(const h4_t*)(a.xl2h + (size_t)(p[j] & 0x00FFFFFFu) * 64 + c0);
#pragma unroll
            for (int j = 0; j < 4; ++j) {
                float ea = (float)(p[j] >> 24) * (1.f / 255.f);
                h4_t z = xv[j] + xrv + wev * (_Float16)ea;
                z = __builtin_elementwise_max(z, z * (_Float16)0.2f);
                float sc = dot4h(z, atv, 0.f);
                sc += __shfl_xor(sc, 1, 64);
                sc += __shfl_xor(sc, 2, 64);
                sc += __shfl_xor(sc, 4, 64);
                float pp = (i + j < deg1) ? __expf(fminf(sc, 60.f)) : 0.f;
                l += pp;
#pragma unroll
                for (int k = 0; k < 4; ++k) acc[k] = fmaf(pp, (float)xv[j][k], acc[k]);
            }
        }
        float inv = 1.f / l;
#pragma unroll
        for (int k = 0; k < 4; ++k) {
            float norm = acc[k] * inv;
            float other = __shfl_xor(norm, 8, 64);
            float v = 0.5f * (norm + other);
            if (r < 8) h2s[nloc][c0 + k] = elu1(v + a.bias2[c0 + k]);
        }
    }
    __syncthreads();
    if (tid < 128) {
        int n = tid >> 3, j = tid & 7;
        int gnode = blockIdx.x * 16 + n;
        if (gnode < a.N) {
            float acc = a.bc[j];
#pragma unroll 8
            for (int d = 0; d < 32; ++d) acc = fmaf(h2s[n][d], a.wc[d * 8 + j], acc);
            a.out[(size_t)gnode * 8 + j] = acc;
        }
    }
}

// ---- launch --------------------------------------------------------------

extern "C" void kernel_launch(void* const* d_in, const int* in_sizes, int n_in,
                              void* d_out, int out_size, void* d_ws, size_t ws_size,
                              hipStream_t stream) {
    const int N = in_sizes[0] / 128;
    const int E = in_sizes[2];
    const int tot = E + N;

    char* ws = (char*)d_ws;
    size_t o = 0;
    auto alloc = [&](size_t bytes) -> void* {
        void* p = ws + o;
        o += (bytes + 255) & ~(size_t)255;
        return p;
    };
    MA a;
    a.x     = (const float*)d_in[0];
    a.ei    = (const int*)d_in[1];
    a.eattr = (const float*)d_in[2];
    a.w1l = (const float*)d_in[3];  a.b1l = (const float*)d_in[4];
    a.w1r = (const float*)d_in[5];  a.b1r = (const float*)d_in[6];
    a.w1e = (const float*)d_in[7];  a.att1 = (const float*)d_in[8];
    a.bias1 = (const float*)d_in[9];
    a.w2l = (const float*)d_in[10]; a.b2l = (const float*)d_in[11];
    a.w2r = (const float*)d_in[12]; a.b2r = (const float*)d_in[13];
    a.w2e = (const float*)d_in[14]; a.att2 = (const float*)d_in[15];
    a.bias2 = (const float*)d_in[16];
    a.wc = (const float*)d_in[17];  a.bc = (const float*)d_in[18];
    a.out = (float*)d_out;

    a.xh   = (_Float16*)alloc((size_t)N * 128 * 2);
    a.xl1h = (_Float16*)alloc((size_t)N * 128 * 2);
    a.xr1h = (_Float16*)alloc((size_t)N * 128 * 2);
    a.h1h  = (_Float16*)alloc((size_t)N * 128 * 2);
    a.xl2h = (_Float16*)alloc((size_t)N * 64 * 2);
    a.xr2h = (_Float16*)alloc((size_t)N * 64 * 2);
    a.p1l  = (_Float16*)alloc(128 * 128 * 2);
    a.p1r  = (_Float16*)alloc(128 * 128 * 2);
    a.p2l  = (_Float16*)alloc(128 * 64 * 2);
    a.p2r  = (_Float16*)alloc(128 * 64 * 2);
    a.cnt  = (int*)alloc((size_t)N * 4);
    a.offb = (int*)alloc((size_t)N * 4);
    a.rank = (int*)alloc((size_t)E * 4);
    a.flags = (unsigned*)alloc(1024 * 4);
    a.part  = (float*)alloc(PRE_BLOCKS * 4);
    a.edges = (unsigned*)alloc((size_t)tot * 4);
    a.N = N;
    a.E = E;
    a.NBs = (N + 255) / 256;
    a.NW = (N + 63) / 64;
    a.invE = 1.0f / (float)E;

    k_pre<<<PRE_BLOCKS + 24, 256, 0, stream>>>(a);
    k_mmcnt<<<a.NW + CNT_BLOCKS, 256, 0, stream>>>(a);
    k_scan<<<a.NBs, 256, 0, stream>>>(a);
    k_fill<<<(E + 255) / 256, 256, 0, stream>>>(a);
    k_node1<<<(N + 3) / 4, 256, 0, stream>>>(a);
    k_mm4<<<(N + 63) / 64, 256, 0, stream>>>(a);
    k_node2<<<(N + 15) / 16, 256, 0, stream>>>(a);
}